// Round 2
// baseline (1027.474 us; speedup 1.0000x reference)
//
#include <hip/hip_runtime.h>

// GCNRegressor: 2-layer GCN (symmetric norm, self-loops) + global mean pool + linear head.
// Strategy: build CSR-by-target once (count/scan/fill), pull-style aggregation
// (no fp32 atomics in hot path), norm coefficients shared across both layers.

#define TPB 256

__global__ void k_init(float* deg, unsigned* cnt, float* gsum, float* gcnt, int n, int g) {
    int i = blockIdx.x * blockDim.x + threadIdx.x;
    if (i < n) { deg[i] = 1.0f; cnt[i] = 0u; }   // deg starts at 1.0 = self-loop weight
    if (i < g) { gsum[i] = 0.0f; gcnt[i] = 0.0f; }
}

__global__ void k_count(const int* __restrict__ col, const float* __restrict__ w,
                        float* deg, unsigned* cnt, int e) {
    int i = blockIdx.x * blockDim.x + threadIdx.x;
    if (i >= e) return;
    int c = col[i];
    atomicAdd(&deg[c], w[i]);
    atomicAdd(&cnt[c], 1u);
}

__global__ void k_rsqrt(float* deg, int n) {
    int i = blockIdx.x * blockDim.x + threadIdx.x;
    if (i < n) deg[i] = rsqrtf(deg[i]);   // deg >= 1 always (self-loop), no zero check needed
}

// single-block exclusive scan of cnt[0..n) -> rowptr[0..n]
__global__ void k_scan(const unsigned* __restrict__ cnt, unsigned* rowptr, int n) {
    __shared__ unsigned lds[1024];
    int t = threadIdx.x;
    int chunk = (n + 1023) >> 10;
    int lo = t * chunk;
    int hi = min(lo + chunk, n);
    unsigned s = 0;
    for (int i = lo; i < hi; ++i) s += cnt[i];
    lds[t] = s;
    __syncthreads();
    for (int off = 1; off < 1024; off <<= 1) {
        unsigned v = (t >= off) ? lds[t - off] : 0u;
        __syncthreads();
        lds[t] += v;
        __syncthreads();
    }
    unsigned run = (t > 0) ? lds[t - 1] : 0u;
    for (int i = lo; i < hi; ++i) { rowptr[i] = run; run += cnt[i]; }
    if (t == 0) rowptr[n] = lds[1023];
}

// scatter edges into CSR slots; rowptr is used as the cursor (after this kernel,
// rowptr[i] == segment_end(i); segment_start(i) == rowptr[i] - cnt[i])
__global__ void k_fill(const int* __restrict__ row, const int* __restrict__ col,
                       const float* __restrict__ w, const float* __restrict__ dinv,
                       unsigned* rowptr, int2* __restrict__ edata, int e) {
    int i = blockIdx.x * blockDim.x + threadIdx.x;
    if (i >= e) return;
    int r = row[i], c = col[i];
    unsigned pos = atomicAdd(&rowptr[c], 1u);
    float nv = dinv[r] * w[i] * dinv[c];
    edata[pos] = make_int2(r, __float_as_int(nv));
}

// hW = x @ W0   (IN_C = 3, HID = 32); thread = (node, channel)
__global__ void k_xw0(const float* __restrict__ x, const float* __restrict__ W0,
                      float* __restrict__ hW, int n) {
    int t = blockIdx.x * blockDim.x + threadIdx.x;
    if (t >= n * 32) return;
    int i = t >> 5, c = t & 31;
    float x0 = x[i * 3 + 0], x1 = x[i * 3 + 1], x2 = x[i * 3 + 2];
    hW[t] = x0 * W0[c] + x1 * W0[32 + c] + x2 * W0[64 + c];
}

// out[i,c] = relu( b[c] + hW[i,c]*dinv[i]^2 + sum_k nrm[k] * hW[src[k], c] )
__global__ void k_agg(const float* __restrict__ hW, const int2* __restrict__ edata,
                      const unsigned* __restrict__ rowptr_end, const unsigned* __restrict__ cnt,
                      const float* __restrict__ dinv, const float* __restrict__ bias,
                      float* __restrict__ out, int n) {
    int t = blockIdx.x * blockDim.x + threadIdx.x;
    if (t >= n * 32) return;
    int i = t >> 5, c = t & 31;
    unsigned end = rowptr_end[i];
    unsigned cn  = cnt[i];
    unsigned k   = end - cn;
    float di = dinv[i];
    float acc = hW[t] * di * di;           // self-loop: norm = dinv^2 * w(=1)
    for (; k < end; ++k) {
        int2 p = edata[k];
        acc = fmaf(__int_as_float(p.y), hW[(p.x << 5) + c], acc);
    }
    out[t] = fmaxf(acc + bias[c], 0.0f);
}

// hW = h @ W1  (32x32), W1 staged in LDS, h staged per-block in LDS
__global__ void k_xw1(const float* __restrict__ h, const float* __restrict__ W1,
                      float* __restrict__ hW, int n) {
    __shared__ float w[1024];
    __shared__ float hl[TPB];
    int t = threadIdx.x;
    for (int j = t; j < 1024; j += TPB) w[j] = W1[j];
    int gt = blockIdx.x * TPB + t;
    int total = n * 32;
    hl[t] = (gt < total) ? h[gt] : 0.0f;
    __syncthreads();
    if (gt < total) {
        int li = t >> 5, c = t & 31;
        const float* hr = hl + (li << 5);
        float acc = 0.0f;
        #pragma unroll
        for (int k = 0; k < 32; ++k) acc = fmaf(hr[k], w[(k << 5) + c], acc);
        hW[gt] = acc;
    }
}

// fold Wr into a per-node scalar, then segment-sum into per-graph bins.
// batch is sorted -> most waves are batch-uniform -> one atomic per wave.
__global__ void k_pool(const float* __restrict__ h, const int* __restrict__ batch,
                       const float* __restrict__ Wr, float* gsum, float* gcnt, int n) {
    int i = blockIdx.x * blockDim.x + threadIdx.x;
    float s = 0.0f;
    int b = -1;
    if (i < n) {
        b = batch[i];
        const float* hr = h + (size_t)i * 32;
        #pragma unroll
        for (int c = 0; c < 32; ++c) s = fmaf(hr[c], Wr[c], s);
    }
    int b0 = __shfl(b, 0, 64);
    // b0 >= 0 guard: an all-out-of-range tail wave has b == b0 == -1 on every
    // lane, which previously took the uniform path and wrote gsum[-1]/gcnt[-1].
    bool uniform = (b0 >= 0) && (__ballot(b == b0) == 0xFFFFFFFFFFFFFFFFULL);
    if (uniform) {
        #pragma unroll
        for (int off = 32; off > 0; off >>= 1) s += __shfl_down(s, off, 64);
        if ((threadIdx.x & 63) == 0) {
            atomicAdd(&gsum[b0], s);
            atomicAdd(&gcnt[b0], 64.0f);
        }
    } else if (i < n) {
        atomicAdd(&gsum[b], s);
        atomicAdd(&gcnt[b], 1.0f);
    }
}

__global__ void k_final(const float* gsum, const float* gcnt, const float* __restrict__ br,
                        float* out, int g) {
    int i = blockIdx.x * blockDim.x + threadIdx.x;
    if (i < g) out[i] = gsum[i] / fmaxf(gcnt[i], 1.0f) + br[0];
}

extern "C" void kernel_launch(void* const* d_in, const int* in_sizes, int n_in,
                              void* d_out, int out_size, void* d_ws, size_t ws_size,
                              hipStream_t stream) {
    const float* x     = (const float*)d_in[0];
    const int*   ei    = (const int*)d_in[1];
    const float* ew    = (const float*)d_in[2];
    const int*   batch = (const int*)d_in[3];
    const float* W0    = (const float*)d_in[4];
    const float* b0    = (const float*)d_in[5];
    const float* W1    = (const float*)d_in[6];
    const float* b1    = (const float*)d_in[7];
    const float* Wr    = (const float*)d_in[8];
    const float* br    = (const float*)d_in[9];
    float* out = (float*)d_out;

    int n = in_sizes[0] / 3;     // 100000
    int e = in_sizes[2];         // 3200000
    int g = out_size;            // 256
    const int* row = ei;         // source (j)
    const int* col = ei + e;     // target (i)

    char* ws = (char*)d_ws;
    size_t off = 0;
    auto alloc = [&](size_t bytes) -> void* {
        void* p = ws + off;
        off += (bytes + 255) & ~(size_t)255;
        return p;
    };
    float*    deg    = (float*)   alloc((size_t)n * 4);          // -> becomes dinv
    unsigned* cnt    = (unsigned*)alloc((size_t)n * 4);
    unsigned* rowptr = (unsigned*)alloc((size_t)(n + 1) * 4);
    int2*     edata  = (int2*)    alloc((size_t)e * 8);          // packed (src, norm)
    float*    hW     = (float*)   alloc((size_t)n * 32 * 4);
    float*    h      = (float*)   alloc((size_t)n * 32 * 4);
    float*    gsum   = (float*)   alloc((size_t)g * 4);
    float*    gcnt   = (float*)   alloc((size_t)g * 4);
    (void)ws_size;

    int nb  = (n + TPB - 1) / TPB;
    int eb  = (e + TPB - 1) / TPB;
    int ncb = (n * 32 + TPB - 1) / TPB;

    k_init  <<<nb,  TPB, 0, stream>>>(deg, cnt, gsum, gcnt, n, g);
    k_count <<<eb,  TPB, 0, stream>>>(col, ew, deg, cnt, e);
    k_rsqrt <<<nb,  TPB, 0, stream>>>(deg, n);
    k_scan  <<<1,  1024, 0, stream>>>(cnt, rowptr, n);
    k_fill  <<<eb,  TPB, 0, stream>>>(row, col, ew, deg, rowptr, edata, e);
    k_xw0   <<<ncb, TPB, 0, stream>>>(x, W0, hW, n);
    k_agg   <<<ncb, TPB, 0, stream>>>(hW, edata, rowptr, cnt, deg, b0, h, n);
    k_xw1   <<<ncb, TPB, 0, stream>>>(h, W1, hW, n);
    k_agg   <<<ncb, TPB, 0, stream>>>(hW, edata, rowptr, cnt, deg, b1, h, n);
    k_pool  <<<nb,  TPB, 0, stream>>>(h, batch, Wr, gsum, gcnt, n);
    k_final <<<1,   TPB, 0, stream>>>(gsum, gcnt, br, out, g);
}

// Round 3
// 698.828 us; speedup vs baseline: 1.4703x; 1.4703x over previous
//
#include <hip/hip_runtime.h>

// GCNRegressor: 2-layer GCN (symmetric norm, self-loops) + global mean pool + linear head.
// R3: single-pass ELL build — ONE packed u64 atomic per edge yields (slot, count,
// fixed-point weighted degree) at once, replacing count+scan+fill (9.6M atomics -> 3.2M).
// dinv is folded into node features so edges store raw w (dinv unknown at build time).
// Bias+ReLU deferred to consumers so an overflow-edge cleanup kernel can atomically
// add into the raw pre-activation buffer (correct for any ELL pad).

#define TPB 256
#define OVF_CAP (1u << 20)
#define FIXS 16777216.0f   // 2^24 fixed point for weighted degree (sum < 256 guaranteed)

typedef unsigned long long u64;

__global__ void k_init(u64* packed, float* gsum, float* gcnt, unsigned* ovf_ctr, int n, int g) {
    int i = blockIdx.x * blockDim.x + threadIdx.x;
    if (i < n) packed[i] = 0ull;
    if (i < g) { gsum[i] = 0.0f; gcnt[i] = 0.0f; }
    if (i == 0) *ovf_ctr = 0u;
}

// one u64 atomic per edge: high32 = count (returned old value = ELL slot),
// low32 = fixed-point weighted degree accumulation.
__global__ void k_build(const int* __restrict__ row, const int* __restrict__ col,
                        const float* __restrict__ w, u64* packed, int2* __restrict__ ell,
                        unsigned* ovf_ctr, int* __restrict__ ovf, int pad, int e) {
    int i = blockIdx.x * blockDim.x + threadIdx.x;
    if (i >= e) return;
    int r = row[i], c = col[i];
    float wv = w[i];
    u64 add = (1ull << 32) | (u64)(unsigned)__float2uint_rn(wv * FIXS);
    u64 old = atomicAdd(&packed[c], add);
    unsigned slot = (unsigned)(old >> 32);
    if (slot < (unsigned)pad) {
        ell[(size_t)c * pad + slot] = make_int2(r, __float_as_int(wv));
    } else {
        unsigned j = atomicAdd(ovf_ctr, 1u);
        if (j < OVF_CAP) ovf[j] = i;   // pad sizing guarantees j < OVF_CAP for this dataset
    }
}

__global__ void k_deg(const u64* __restrict__ packed, float* dinv, unsigned* cnt, int pad, int n) {
    int i = blockIdx.x * blockDim.x + threadIdx.x;
    if (i >= n) return;
    u64 pk = packed[i];
    float deg = 1.0f + (float)(unsigned)(pk & 0xffffffffull) * (1.0f / FIXS);  // +1 = self loop
    dinv[i] = rsqrtf(deg);
    unsigned c = (unsigned)(pk >> 32);
    cnt[i] = c < (unsigned)pad ? c : (unsigned)pad;
}

// hW'[i,c] = dinv[i] * (x @ W0)[i,c]   (IN_C = 3, HID = 32)
__global__ void k_xw0(const float* __restrict__ x, const float* __restrict__ W0,
                      const float* __restrict__ dinv, float* __restrict__ hW, int n) {
    int t = blockIdx.x * blockDim.x + threadIdx.x;
    if (t >= n * 32) return;
    int i = t >> 5, c = t & 31;
    float x0 = x[i * 3 + 0], x1 = x[i * 3 + 1], x2 = x[i * 3 + 2];
    hW[t] = dinv[i] * (x0 * W0[c] + x1 * W0[32 + c] + x2 * W0[64 + c]);
}

// t[i,c] = dinv[i] * (hW'[i,c] + sum_k w_k * hW'[r_k, c])     (no bias/relu here)
__global__ void k_agg(const float* __restrict__ hW, const int2* __restrict__ ell,
                      const unsigned* __restrict__ cnt, const float* __restrict__ dinv,
                      float* __restrict__ t_out, int pad, int n) {
    int t = blockIdx.x * blockDim.x + threadIdx.x;
    if (t >= n * 32) return;
    int i = t >> 5, c = t & 31;
    unsigned cn = cnt[i];
    const int2* rp = ell + (size_t)i * pad;
    float acc = hW[t];                      // self-loop (w = 1)
    for (unsigned k = 0; k < cn; ++k) {
        int2 p = rp[k];
        acc = fmaf(__int_as_float(p.y), hW[(p.x << 5) + c], acc);
    }
    t_out[t] = dinv[i] * acc;
}

// overflow edges (slot >= pad): scatter-atomic into pre-activation buffer.
__global__ void k_ovf(const int* __restrict__ row, const int* __restrict__ col,
                      const float* __restrict__ w, const unsigned* __restrict__ ovf_ctr,
                      const int* __restrict__ ovf, const float* __restrict__ dinv,
                      const float* __restrict__ hW, float* t_out) {
    unsigned cn = *ovf_ctr;
    if (cn > OVF_CAP) cn = OVF_CAP;
    unsigned total = cn * 32u;
    unsigned stride = gridDim.x * blockDim.x;
    for (unsigned idx = blockIdx.x * blockDim.x + threadIdx.x; idx < total; idx += stride) {
        int e = ovf[idx >> 5];
        int ch = idx & 31;
        int r = row[e], c = col[e];
        atomicAdd(&t_out[(c << 5) + ch], dinv[c] * w[e] * hW[(r << 5) + ch]);
    }
}

// h = relu(t1 + b0); hW2'[i,c] = dinv[i] * (h @ W1)[i,c]   (32x32, W1 in LDS)
__global__ void k_xw1(const float* __restrict__ t1, const float* __restrict__ b0,
                      const float* __restrict__ W1, const float* __restrict__ dinv,
                      float* __restrict__ hW, int n) {
    __shared__ float w[1024];
    __shared__ float hl[TPB];
    int t = threadIdx.x;
    for (int j = t; j < 1024; j += TPB) w[j] = W1[j];
    int gt = blockIdx.x * TPB + t;
    int total = n * 32;
    hl[t] = (gt < total) ? fmaxf(t1[gt] + b0[t & 31], 0.0f) : 0.0f;
    __syncthreads();
    if (gt < total) {
        int li = t >> 5, c = t & 31;
        const float* hr = hl + (li << 5);
        float acc = 0.0f;
        #pragma unroll
        for (int k = 0; k < 32; ++k) acc = fmaf(hr[k], w[(k << 5) + c], acc);
        hW[gt] = dinv[gt >> 5] * acc;
    }
}

// s_i = sum_c relu(t2[i,c] + b1[c]) * Wr[c]; segment-sum into per-graph bins.
// batch is sorted -> most waves are batch-uniform -> one atomic per wave.
__global__ void k_pool(const float* __restrict__ t2, const float* __restrict__ b1,
                       const int* __restrict__ batch, const float* __restrict__ Wr,
                       float* gsum, float* gcnt, int n) {
    int i = blockIdx.x * blockDim.x + threadIdx.x;
    float s = 0.0f;
    int b = -1;
    if (i < n) {
        b = batch[i];
        const float* hr = t2 + (size_t)i * 32;
        #pragma unroll
        for (int c = 0; c < 32; ++c) s = fmaf(fmaxf(hr[c] + b1[c], 0.0f), Wr[c], s);
    }
    int b0v = __shfl(b, 0, 64);
    bool uniform = (b0v >= 0) && (__ballot(b == b0v) == 0xFFFFFFFFFFFFFFFFULL);
    if (uniform) {
        #pragma unroll
        for (int off = 32; off > 0; off >>= 1) s += __shfl_down(s, off, 64);
        if ((threadIdx.x & 63) == 0) {
            atomicAdd(&gsum[b0v], s);
            atomicAdd(&gcnt[b0v], 64.0f);
        }
    } else if (i < n) {
        atomicAdd(&gsum[b], s);
        atomicAdd(&gcnt[b], 1.0f);
    }
}

__global__ void k_final(const float* gsum, const float* gcnt, const float* __restrict__ br,
                        float* out, int g) {
    int i = blockIdx.x * blockDim.x + threadIdx.x;
    if (i < g) out[i] = gsum[i] / fmaxf(gcnt[i], 1.0f) + br[0];
}

extern "C" void kernel_launch(void* const* d_in, const int* in_sizes, int n_in,
                              void* d_out, int out_size, void* d_ws, size_t ws_size,
                              hipStream_t stream) {
    const float* x     = (const float*)d_in[0];
    const int*   ei    = (const int*)d_in[1];
    const float* ew    = (const float*)d_in[2];
    const int*   batch = (const int*)d_in[3];
    const float* W0    = (const float*)d_in[4];
    const float* b0    = (const float*)d_in[5];
    const float* W1    = (const float*)d_in[6];
    const float* b1    = (const float*)d_in[7];
    const float* Wr    = (const float*)d_in[8];
    const float* br    = (const float*)d_in[9];
    float* out = (float*)d_out;

    int n = in_sizes[0] / 3;     // 100000
    int e = in_sizes[2];         // 3200000
    int g = out_size;            // 256
    const int* row = ei;         // source (j)
    const int* col = ei + e;     // target (i)

    char* ws = (char*)d_ws;
    size_t off = 0;
    auto alloc = [&](size_t bytes) -> void* {
        void* p = ws + off;
        off += (bytes + 255) & ~(size_t)255;
        return p;
    };
    u64*      packed  = (u64*)     alloc((size_t)n * 8);
    float*    dinv    = (float*)   alloc((size_t)n * 4);
    unsigned* cnt     = (unsigned*)alloc((size_t)n * 4);
    float*    hW      = (float*)   alloc((size_t)n * 32 * 4);   // dinv-folded features
    float*    tbuf    = (float*)   alloc((size_t)n * 32 * 4);   // pre-activation agg output
    float*    gsum    = (float*)   alloc((size_t)g * 4);
    float*    gcnt    = (float*)   alloc((size_t)g * 4);
    unsigned* ovf_ctr = (unsigned*)alloc(256);
    int*      ovf     = (int*)     alloc((size_t)OVF_CAP * 4);

    // ELL pad from remaining workspace (ws >= 52.4 MB known -> pad >= 26; overflow
    // list handles the Poisson(32) tail for any pad; pad 96 -> zero overflow).
    size_t remain = (ws_size > off) ? (ws_size - off) : 0;
    int pad = (int)(remain / ((size_t)n * 8));
    if (pad > 96) pad = 96;
    if (pad < 8)  pad = 8;
    int2* ell = (int2*)alloc((size_t)n * pad * 8);

    int nb  = (n + TPB - 1) / TPB;
    int eb  = (e + TPB - 1) / TPB;
    int ncb = (n * 32 + TPB - 1) / TPB;

    k_init  <<<nb,  TPB, 0, stream>>>(packed, gsum, gcnt, ovf_ctr, n, g);
    k_build <<<eb,  TPB, 0, stream>>>(row, col, ew, packed, ell, ovf_ctr, ovf, pad, e);
    k_deg   <<<nb,  TPB, 0, stream>>>(packed, dinv, cnt, pad, n);
    k_xw0   <<<ncb, TPB, 0, stream>>>(x, W0, dinv, hW, n);
    k_agg   <<<ncb, TPB, 0, stream>>>(hW, ell, cnt, dinv, tbuf, pad, n);
    k_ovf   <<<512, TPB, 0, stream>>>(row, col, ew, ovf_ctr, ovf, dinv, hW, tbuf);
    k_xw1   <<<ncb, TPB, 0, stream>>>(tbuf, b0, W1, dinv, hW, n);
    k_agg   <<<ncb, TPB, 0, stream>>>(hW, ell, cnt, dinv, tbuf, pad, n);
    k_ovf   <<<512, TPB, 0, stream>>>(row, col, ew, ovf_ctr, ovf, dinv, hW, tbuf);
    k_pool  <<<nb,  TPB, 0, stream>>>(tbuf, b1, batch, Wr, gsum, gcnt, n);
    k_final <<<1,   TPB, 0, stream>>>(gsum, gcnt, br, out, g);
}